// Round 1
// baseline (7839.561 us; speedup 1.0000x reference)
//
#include <hip/hip_runtime.h>

#define NIMG 4
#define BATCH 8
#define SEQ 576
#define DIM 256
#define NHEAD 8
#define DHEAD 32
#define NLAYER 6
#define TD 768          // 3*DIM
#define KPATCH 768      // 3*16*16
#define MLPD 512
#define SS (SEQ*SEQ)

// ---------------- conv weight transpose: wT[ni][k][d] = w[ni][d][k] ----------------
__global__ void k_transpose_w(const float* __restrict__ w, float* __restrict__ wT) {
  int idx = blockIdx.x * 256 + threadIdx.x;       // 4*768*256 total
  int d = idx & 255;
  int t = idx >> 8;
  int ni = t / 768;
  int k = t - ni * 768;
  wT[idx] = w[(size_t)ni * 196608 + (size_t)d * 768 + k];
}

// ---------------- patch embed: pe[ni][b][s][d] = conv + bias + pos ----------------
__global__ __launch_bounds__(256) void k_patch_embed(
    const float* __restrict__ x, const float* __restrict__ wT,
    const float* __restrict__ cb, const float* __restrict__ pos,
    float* __restrict__ pe) {
  __shared__ float patch[8][KPATCH];
  const int ni = blockIdx.z, b = blockIdx.y;
  const int s0 = blockIdx.x * 8;
  const int tid = threadIdx.x;
  for (int e = tid; e < 8 * KPATCH; e += 256) {
    int sp = e / KPATCH, k = e - sp * KPATCH;
    int s = s0 + sp;
    int c = k >> 8, r = k & 255, i = r >> 4, j = r & 15;
    int py = s / 24, px = s - py * 24;
    patch[sp][k] = x[((size_t)(b * 12 + ni * 3 + c) * 384 + py * 16 + i) * 384 + px * 16 + j];
  }
  __syncthreads();
  const int d = tid;
  float acc[8] = {};
  const float* wp = wT + (size_t)ni * 196608 + d;
  for (int k = 0; k < KPATCH; ++k) {
    float wv = wp[(size_t)k * 256];
    #pragma unroll
    for (int sp = 0; sp < 8; ++sp) acc[sp] = fmaf(patch[sp][k], wv, acc[sp]);
  }
  float bias = cb[ni * 256 + d];
  size_t base = ((size_t)(ni * BATCH + b) * SEQ + s0) * DIM + d;
  #pragma unroll
  for (int sp = 0; sp < 8; ++sp)
    pe[base + (size_t)sp * 256] = acc[sp] + bias + pos[(s0 + sp) * 256 + d];
}

// ---------------- fp32 GEMM: C[M,N] = A[M,K] @ W[N,K]^T + bias[N] ----------------
// 128x128 tile, BK=16, 256 threads, 8x8 per thread (cols/rows interleaved by 16)
__global__ __launch_bounds__(256) void k_gemm_bt(
    const float* __restrict__ A, const float* __restrict__ W,
    const float* __restrict__ bias, float* __restrict__ C,
    int M, int N, int K) {
  __shared__ float As[16][132];
  __shared__ float Ws[16][132];
  const int bm = blockIdx.y * 128, bn = blockIdx.x * 128;
  const int tid = threadIdx.x;
  const int tx = tid & 15, ty = tid >> 4;
  float acc[8][8] = {};
  for (int k0 = 0; k0 < K; k0 += 16) {
    __syncthreads();
    #pragma unroll
    for (int half = 0; half < 2; ++half) {
      int f = tid + half * 256;           // float4 id in [0,512)
      int r = f >> 2, ko = f & 3;
      float4 va = reinterpret_cast<const float4*>(A + (size_t)(bm + r) * K + k0)[ko];
      As[ko * 4 + 0][r] = va.x; As[ko * 4 + 1][r] = va.y;
      As[ko * 4 + 2][r] = va.z; As[ko * 4 + 3][r] = va.w;
      float4 vw = reinterpret_cast<const float4*>(W + (size_t)(bn + r) * K + k0)[ko];
      Ws[ko * 4 + 0][r] = vw.x; Ws[ko * 4 + 1][r] = vw.y;
      Ws[ko * 4 + 2][r] = vw.z; Ws[ko * 4 + 3][r] = vw.w;
    }
    __syncthreads();
    #pragma unroll
    for (int kk = 0; kk < 16; ++kk) {
      float a[8], bv[8];
      #pragma unroll
      for (int i = 0; i < 8; ++i) a[i] = As[kk][ty + 16 * i];
      #pragma unroll
      for (int j = 0; j < 8; ++j) bv[j] = Ws[kk][tx + 16 * j];
      #pragma unroll
      for (int i = 0; i < 8; ++i)
        #pragma unroll
        for (int j = 0; j < 8; ++j)
          acc[i][j] = fmaf(a[i], bv[j], acc[i][j]);
    }
  }
  #pragma unroll
  for (int i = 0; i < 8; ++i) {
    size_t row = (size_t)(bm + ty + 16 * i) * N + bn;
    #pragma unroll
    for (int j = 0; j < 8; ++j)
      C[row + tx + 16 * j] = acc[i][j] + bias[bn + tx + 16 * j];
  }
}

// ---------------- fused attention for one layer ----------------
// block: (qtile 16 rows, b, ni); loops heads; qkv row layout [ni,b,s][768] (q|k|v)
__global__ __launch_bounds__(256) void k_attn(
    const float* __restrict__ qkv, float* __restrict__ obuf,
    float* __restrict__ attn_l) {
  __shared__ float sc[16][577];
  __shared__ float kv[64][33];
  __shared__ float qs[16][33];
  const int ni = blockIdx.z, b = blockIdx.y;
  const int qt16 = blockIdx.x * 16;
  const int tid = threadIdx.x;
  const int qi = tid >> 4, tl = tid & 15;       // score/softmax mapping
  const int qi2 = tid >> 5, dh = tid & 31;      // PV mapping
  const size_t base_s = (size_t)(ni * BATCH + b) * SEQ;
  float av[36] = {};                            // head-averaged attention accumulator

  for (int h = 0; h < NHEAD; ++h) {
    // ---- stage Q tile ----
    for (int e = tid; e < 16 * 32; e += 256) {
      int qq = e >> 5, dd = e & 31;
      qs[qq][dd] = qkv[(base_s + qt16 + qq) * TD + h * 32 + dd];
    }
    __syncthreads();
    float qr[32];
    #pragma unroll
    for (int dd = 0; dd < 32; ++dd) qr[dd] = qs[qi][dd];
    // ---- scores = q . k / sqrt(32) ----
    for (int kt = 0; kt < 9; ++kt) {
      __syncthreads();
      for (int e = tid; e < 64 * 32; e += 256) {
        int r = e >> 5, dd = e & 31;
        kv[r][dd] = qkv[(base_s + kt * 64 + r) * TD + 256 + h * 32 + dd];
      }
      __syncthreads();
      #pragma unroll
      for (int tt = 0; tt < 4; ++tt) {
        float a = 0.f;
        #pragma unroll
        for (int dd = 0; dd < 32; ++dd) a = fmaf(qr[dd], kv[tt * 16 + tl][dd], a);
        sc[qi][kt * 64 + tt * 16 + tl] = a * 0.17677669529663687f;
      }
    }
    // thread (qi,tl) wrote exactly cols t = tl+16u -> softmax reads only own cols
    float mx = -1e30f;
    #pragma unroll
    for (int u = 0; u < 36; ++u) mx = fmaxf(mx, sc[qi][tl + 16 * u]);
    #pragma unroll
    for (int m = 1; m < 16; m <<= 1) mx = fmaxf(mx, __shfl_xor(mx, m, 64));
    float sum = 0.f;
    #pragma unroll
    for (int u = 0; u < 36; ++u) {
      float e = __expf(sc[qi][tl + 16 * u] - mx);
      sc[qi][tl + 16 * u] = e;
      sum += e;
    }
    #pragma unroll
    for (int m = 1; m < 16; m <<= 1) sum += __shfl_xor(sum, m, 64);
    float inv = 1.0f / sum;
    #pragma unroll
    for (int u = 0; u < 36; ++u) {
      float p = sc[qi][tl + 16 * u] * inv;
      sc[qi][tl + 16 * u] = p;
      av[u] += p;
    }
    // ---- PV: o[qi][dh] = sum_t p * v ----
    float o0 = 0.f, o1 = 0.f;
    for (int vt = 0; vt < 9; ++vt) {
      __syncthreads();   // also serves as post-softmax barrier on first iter
      for (int e = tid; e < 64 * 32; e += 256) {
        int r = e >> 5, dd = e & 31;
        kv[r][dd] = qkv[(base_s + vt * 64 + r) * TD + 512 + h * 32 + dd];
      }
      __syncthreads();
      #pragma unroll 8
      for (int r = 0; r < 64; ++r) {
        float vv = kv[r][dh];
        o0 = fmaf(sc[qi2][vt * 64 + r], vv, o0);
        o1 = fmaf(sc[qi2 + 8][vt * 64 + r], vv, o1);
      }
    }
    obuf[(base_s + qt16 + qi2) * DIM + h * 32 + dh] = o0;
    obuf[(base_s + qt16 + qi2 + 8) * DIM + h * 32 + dh] = o1;
    __syncthreads();   // protect sc/qs/kv before next head
  }
  // ---- write head-averaged attention ----
  size_t abase = (size_t)(ni * BATCH + b) * SS + (size_t)(qt16 + qi) * SEQ + tl;
  #pragma unroll
  for (int u = 0; u < 36; ++u) attn_l[abase + 16 * u] = av[u] * 0.125f;
}

// ---------------- head ----------------
__global__ void k_feat(const float* __restrict__ pe, float* __restrict__ feat) {
  int idx = blockIdx.x * 256 + threadIdx.x;     // 8*1024
  int b = idx >> 10, c = idx & 1023;
  int ni = c >> 8, d = c & 255;
  const float* p = pe + (size_t)(ni * BATCH + b) * SEQ * DIM + d;
  float sum = 0.f;
  for (int s = 0; s < SEQ; ++s) sum += p[(size_t)s * DIM];
  feat[idx] = sum * (1.0f / 576.0f);
}

__global__ void k_head1(const float* __restrict__ feat, const float* __restrict__ w1,
                        const float* __restrict__ b1, float* __restrict__ h) {
  int idx = blockIdx.x * 256 + threadIdx.x;     // 8*512
  int b = idx >> 9, m = idx & 511;
  const float* f = feat + b * 1024;
  const float* w = w1 + (size_t)m * 1024;
  float acc = 0.f;
  for (int k = 0; k < 1024; ++k) acc = fmaf(f[k], w[k], acc);
  h[idx] = fmaxf(acc + b1[m], 0.f);
}

__global__ void k_head2(const float* __restrict__ h, const float* __restrict__ w2,
                        const float* __restrict__ b2, float* __restrict__ out) {
  int b = blockIdx.x;
  int lane = threadIdx.x;
  float acc = 0.f;
  for (int m = lane; m < 512; m += 64) acc = fmaf(h[b * 512 + m], w2[m], acc);
  #pragma unroll
  for (int m = 1; m < 64; m <<= 1) acc += __shfl_xor(acc, m, 64);
  if (lane == 0) out[b] = acc + b2[0];
}

extern "C" void kernel_launch(void* const* d_in, const int* in_sizes, int n_in,
                              void* d_out, int out_size, void* d_ws, size_t ws_size,
                              hipStream_t stream) {
  const float* x      = (const float*)d_in[0];
  const float* conv_w = (const float*)d_in[1];
  const float* conv_b = (const float*)d_in[2];
  const float* pos    = (const float*)d_in[3];
  const float* in_w   = (const float*)d_in[4];
  const float* in_b   = (const float*)d_in[5];
  const float* ow     = (const float*)d_in[6];
  const float* ob     = (const float*)d_in[7];
  const float* w1     = (const float*)d_in[8];
  const float* b1     = (const float*)d_in[9];
  const float* w2     = (const float*)d_in[10];
  const float* b2     = (const float*)d_in[11];
  float* out  = (float*)d_out;
  float* attn = out + 8;

  float* ws   = (float*)d_ws;
  float* wT   = ws;                         // 786432
  float* peA  = wT + 786432;                // 4718592
  float* qkv  = peA + 4718592;              // 14155776
  float* oB   = qkv + 14155776;             // 4718592
  float* feat = oB + 4718592;               // 8192
  float* hbuf = feat + 8192;                // 4096

  k_transpose_w<<<3072, 256, 0, stream>>>(conv_w, wT);
  k_patch_embed<<<dim3(72, BATCH, NIMG), 256, 0, stream>>>(x, wT, conv_b, pos, peA);
  for (int l = 0; l < NLAYER; ++l) {
    k_gemm_bt<<<dim3(6, 144), 256, 0, stream>>>(
        peA, in_w + (size_t)l * TD * DIM, in_b + l * TD, qkv, 18432, TD, DIM);
    k_attn<<<dim3(36, BATCH, NIMG), 256, 0, stream>>>(
        qkv, oB, attn + (size_t)l * NIMG * BATCH * SS);
    k_gemm_bt<<<dim3(2, 144), 256, 0, stream>>>(
        oB, ow + (size_t)l * DIM * DIM, ob + l * DIM, peA, 18432, DIM, DIM);
  }
  k_feat<<<32, 256, 0, stream>>>(peA, feat);
  k_head1<<<16, 256, 0, stream>>>(feat, w1, b1, hbuf);
  k_head2<<<BATCH, 64, 0, stream>>>(hbuf, w2, b2, out);
}

// Round 2
// 6486.194 us; speedup vs baseline: 1.2087x; 1.2087x over previous
//
#include <hip/hip_runtime.h>

#define NIMG 4
#define BATCH 8
#define SEQ 576
#define DIM 256
#define NHEAD 8
#define DHEAD 32
#define NLAYER 6
#define TD 768          // 3*DIM
#define KPATCH 768      // 3*16*16
#define MLPD 512
#define SS (SEQ*SEQ)

typedef float f32x4 __attribute__((ext_vector_type(4)));
typedef short s16x8 __attribute__((ext_vector_type(8)));

static __device__ __forceinline__ unsigned short f2bf(float f) {
  __bf16 h = (__bf16)f;
  return __builtin_bit_cast(unsigned short, h);
}
static __device__ __forceinline__ float bf2f(unsigned short u) {
  return __builtin_bit_cast(float, (unsigned)u << 16);
}

// ---------------- conv weight transpose: wT[ni][k][d] = w[ni][d][k] ----------------
__global__ void k_transpose_w(const float* __restrict__ w, float* __restrict__ wT) {
  int idx = blockIdx.x * 256 + threadIdx.x;
  int d = idx & 255;
  int t = idx >> 8;
  int ni = t / 768;
  int k = t - ni * 768;
  wT[idx] = w[(size_t)ni * 196608 + (size_t)d * 768 + k];
}

// ---------------- patch embed ----------------
__global__ __launch_bounds__(256) void k_patch_embed(
    const float* __restrict__ x, const float* __restrict__ wT,
    const float* __restrict__ cb, const float* __restrict__ pos,
    float* __restrict__ pe) {
  __shared__ float patch[8][KPATCH];
  const int ni = blockIdx.z, b = blockIdx.y;
  const int s0 = blockIdx.x * 8;
  const int tid = threadIdx.x;
  for (int e = tid; e < 8 * KPATCH; e += 256) {
    int sp = e / KPATCH, k = e - sp * KPATCH;
    int s = s0 + sp;
    int c = k >> 8, r = k & 255, i = r >> 4, j = r & 15;
    int py = s / 24, px = s - py * 24;
    patch[sp][k] = x[((size_t)(b * 12 + ni * 3 + c) * 384 + py * 16 + i) * 384 + px * 16 + j];
  }
  __syncthreads();
  const int d = tid;
  float acc[8] = {};
  const float* wp = wT + (size_t)ni * 196608 + d;
  for (int k = 0; k < KPATCH; ++k) {
    float wv = wp[(size_t)k * 256];
    #pragma unroll
    for (int sp = 0; sp < 8; ++sp) acc[sp] = fmaf(patch[sp][k], wv, acc[sp]);
  }
  float bias = cb[ni * 256 + d];
  size_t base = ((size_t)(ni * BATCH + b) * SEQ + s0) * DIM + d;
  #pragma unroll
  for (int sp = 0; sp < 8; ++sp)
    pe[base + (size_t)sp * 256] = acc[sp] + bias + pos[(s0 + sp) * 256 + d];
}

// ---------------- fp32 GEMM: C[M,N] = A[M,K] @ W[N,K]^T + bias[N] ----------------
__global__ __launch_bounds__(256) void k_gemm_bt(
    const float* __restrict__ A, const float* __restrict__ W,
    const float* __restrict__ bias, float* __restrict__ C,
    int M, int N, int K) {
  __shared__ float As[16][132];
  __shared__ float Ws[16][132];
  const int bm = blockIdx.y * 128, bn = blockIdx.x * 128;
  const int tid = threadIdx.x;
  const int tx = tid & 15, ty = tid >> 4;
  float acc[8][8] = {};
  for (int k0 = 0; k0 < K; k0 += 16) {
    __syncthreads();
    #pragma unroll
    for (int half = 0; half < 2; ++half) {
      int f = tid + half * 256;
      int r = f >> 2, ko = f & 3;
      float4 va = reinterpret_cast<const float4*>(A + (size_t)(bm + r) * K + k0)[ko];
      As[ko * 4 + 0][r] = va.x; As[ko * 4 + 1][r] = va.y;
      As[ko * 4 + 2][r] = va.z; As[ko * 4 + 3][r] = va.w;
      float4 vw = reinterpret_cast<const float4*>(W + (size_t)(bn + r) * K + k0)[ko];
      Ws[ko * 4 + 0][r] = vw.x; Ws[ko * 4 + 1][r] = vw.y;
      Ws[ko * 4 + 2][r] = vw.z; Ws[ko * 4 + 3][r] = vw.w;
    }
    __syncthreads();
    #pragma unroll
    for (int kk = 0; kk < 16; ++kk) {
      float a[8], bv[8];
      #pragma unroll
      for (int i = 0; i < 8; ++i) a[i] = As[kk][ty + 16 * i];
      #pragma unroll
      for (int j = 0; j < 8; ++j) bv[j] = Ws[kk][tx + 16 * j];
      #pragma unroll
      for (int i = 0; i < 8; ++i)
        #pragma unroll
        for (int j = 0; j < 8; ++j)
          acc[i][j] = fmaf(a[i], bv[j], acc[i][j]);
    }
  }
  #pragma unroll
  for (int i = 0; i < 8; ++i) {
    size_t row = (size_t)(bm + ty + 16 * i) * N + bn;
    #pragma unroll
    for (int j = 0; j < 8; ++j)
      C[row + tx + 16 * j] = acc[i][j] + bias[bn + tx + 16 * j];
  }
}

// ---------------- MFMA fused attention (hi/lo bf16 split ~= fp32 accuracy) ----------------
// block: 32 q-rows of one (ni,b) pair; 4 waves = 2 row-tiles x 2 col-parities; heads looped.
// LDS: P_hi[32][72 slots][8]bf16 (36864) | P_lo (36864) | KV dbuf 2x4096 = 81920 B total.
__global__ __launch_bounds__(256, 2) void k_attn2(
    const float* __restrict__ qkv, float* __restrict__ obuf,
    float* __restrict__ attn_l) {
  __shared__ __align__(16) unsigned char sm[81920];
  unsigned char* Phi = sm;
  unsigned char* Plo = sm + 36864;
  unsigned char* KV  = sm + 73728;

  const int tid = threadIdx.x;
  const int bid = blockIdx.x;
  const int pair = bid & 31;          // same pair -> same XCD (bid%8 const)
  const int qt = bid >> 5;
  const int q0 = qt * 32;
  const int lane = tid & 63;
  const int w = tid >> 6;
  const int rt = w >> 1, par = w & 1;
  const int g = lane >> 4, lx = lane & 15;
  const size_t base_s = (size_t)pair * SEQ;

  // stage-load mapping (all 256 threads)
  const int srow = tid >> 3;          // 0..31
  const int d0 = (tid & 7) * 4;       // 0..28
  const bool kodd = (srow & 1);
  const int kp = srow & ~1;

  f32x4 av[18];
  #pragma unroll
  for (int u = 0; u < 18; ++u) av[u] = f32x4{0.f, 0.f, 0.f, 0.f};

  for (int h = 0; h < NHEAD; ++h) {
    // ---- Q A-frags (scaled, hi/lo split), direct from global ----
    const float* qp = qkv + (base_s + q0 + 16 * rt + lx) * TD + h * 32 + g * 8;
    s16x8 qhi, qlo;
    #pragma unroll
    for (int j = 0; j < 8; ++j) {
      float v = qp[j] * 0.17677669529663687f;
      unsigned short hb = f2bf(v);
      qhi[j] = (short)hb;
      qlo[j] = (short)f2bf(v - bf2f(hb));
    }

    auto gload = [&](int off, int c) -> float4 {
      return *(const float4*)(qkv + (base_s + c * 32 + srow) * TD + off + h * 32 + d0);
    };
    // K chunk: [32 rows][slots: hi 0-3 | lo 4-7][8 bf16], slot phys = sl ^ (row&7)
    auto kwrite = [&](unsigned char* buf, float4 v) {
      unsigned short hb[4], lb[4];
      #pragma unroll
      for (int i = 0; i < 4; ++i) {
        float xx = (&v.x)[i];
        hb[i] = f2bf(xx);
        lb[i] = f2bf(xx - bf2f(hb[i]));
      }
      unsigned long long hw = (unsigned long long)hb[0] | ((unsigned long long)hb[1] << 16) |
                              ((unsigned long long)hb[2] << 32) | ((unsigned long long)hb[3] << 48);
      unsigned long long lw = (unsigned long long)lb[0] | ((unsigned long long)lb[1] << 16) |
                              ((unsigned long long)lb[2] << 32) | ((unsigned long long)lb[3] << 48);
      int ph = (d0 >> 3) ^ (srow & 7);
      int pl = (4 + (d0 >> 3)) ^ (srow & 7);
      *(unsigned long long*)(buf + srow * 128 + (ph << 4) + ((d0 & 4) << 1)) = hw;
      *(unsigned long long*)(buf + srow * 128 + (pl << 4) + ((d0 & 4) << 1)) = lw;
    };
    // V chunk transposed: [32 d][slots: hi k 0-3 | lo 4-7][8 bf16]
    auto vwrite = [&](unsigned char* buf, float4 v) {
      #pragma unroll
      for (int i = 0; i < 4; ++i) {
        float mine = (&v.x)[i];
        float oth = __shfl_xor(mine, 8);
        int d = d0 + i;
        unsigned wd;
        int slot;
        if (!kodd) {           // hi halves of (k, k+1) = (mine, partner)
          wd = (unsigned)f2bf(mine) | ((unsigned)f2bf(oth) << 16);
          slot = kp >> 3;
        } else {               // lo halves of (k-1, k) = (partner, mine)
          unsigned short l0 = f2bf(oth - bf2f(f2bf(oth)));
          unsigned short l1 = f2bf(mine - bf2f(f2bf(mine)));
          wd = (unsigned)l0 | ((unsigned)l1 << 16);
          slot = 4 + (kp >> 3);
        }
        *(unsigned*)(buf + d * 128 + (((slot) ^ (d & 7)) << 4) + (kp & 7) * 2) = wd;
      }
    };

    // ---- scores: S[c] = Q . K^T for 18 chunks of 32 keys ----
    f32x4 S[18];
    float4 ld = gload(256, 0);
    __syncthreads();                      // KV area free (prev head readout done)
    kwrite(KV, ld);
    ld = gload(256, 1);
    #pragma unroll
    for (int c = 0; c < 18; ++c) {
      __syncthreads();
      if (c < 17) kwrite(KV + ((c + 1) & 1) * 4096, ld);
      if (c < 16) ld = gload(256, c + 2);
      unsigned char* kb = KV + (c & 1) * 4096;
      int krow = 16 * par + lx;
      s16x8 khi = *(const s16x8*)(kb + krow * 128 + (((g) ^ (krow & 7)) << 4));
      s16x8 klo = *(const s16x8*)(kb + krow * 128 + (((g + 4) ^ (krow & 7)) << 4));
      f32x4 a = {0.f, 0.f, 0.f, 0.f};
      a = __builtin_amdgcn_mfma_f32_16x16x32_bf16(qlo, khi, a, 0, 0, 0);
      a = __builtin_amdgcn_mfma_f32_16x16x32_bf16(qhi, klo, a, 0, 0, 0);
      a = __builtin_amdgcn_mfma_f32_16x16x32_bf16(qhi, khi, a, 0, 0, 0);
      S[c] = a;
    }

    // ---- softmax (rows split across col-parity waves; exchange via scratch) ----
    float m0[4];
    #pragma unroll
    for (int r = 0; r < 4; ++r) {
      float m = S[0][r];
      #pragma unroll
      for (int u = 1; u < 18; ++u) m = fmaxf(m, S[u][r]);
      #pragma unroll
      for (int msk = 1; msk < 16; msk <<= 1) m = fmaxf(m, __shfl_xor(m, msk));
      m0[r] = m;
    }
    __syncthreads();                      // A0: all K reads done; kvbuf0 -> scratch
    ld = gload(512, 0);                   // V0 loads in flight over softmax
    float* scrM = (float*)KV;
    float* scrL = (float*)(KV + 256);
    if (lx == 0) {
      #pragma unroll
      for (int r = 0; r < 4; ++r) scrM[(par * 2 + rt) * 16 + 4 * g + r] = m0[r];
    }
    __syncthreads();                      // A1
    #pragma unroll
    for (int r = 0; r < 4; ++r)
      m0[r] = fmaxf(m0[r], scrM[((par ^ 1) * 2 + rt) * 16 + 4 * g + r]);
    float lsum[4] = {0.f, 0.f, 0.f, 0.f};
    #pragma unroll
    for (int u = 0; u < 18; ++u)
      #pragma unroll
      for (int r = 0; r < 4; ++r) {
        float e = __expf(S[u][r] - m0[r]);
        S[u][r] = e;
        lsum[r] += e;
      }
    #pragma unroll
    for (int r = 0; r < 4; ++r)
      #pragma unroll
      for (int msk = 1; msk < 16; msk <<= 1) lsum[r] += __shfl_xor(lsum[r], msk);
    if (lx == 0) {
      #pragma unroll
      for (int r = 0; r < 4; ++r) scrL[(par * 2 + rt) * 16 + 4 * g + r] = lsum[r];
    }
    __syncthreads();                      // B1
    float inv[4];
    #pragma unroll
    for (int r = 0; r < 4; ++r)
      inv[r] = 1.0f / (lsum[r] + scrL[((par ^ 1) * 2 + rt) * 16 + 4 * g + r]);
    __syncthreads();                      // B2: scratch reads done -> kvbuf0 writable
    vwrite(KV, ld);                       // V0
    ld = gload(512, 1);

    // ---- P = S*inv -> av (C-frag regs) + P_hi/P_lo to LDS (paired b32 writes) ----
    #pragma unroll
    for (int u = 0; u < 18; ++u) {
      int colb = (2 * u + par) * 16;
      #pragma unroll
      for (int r = 0; r < 4; ++r) {
        float pv_ = S[u][r] * inv[r];
        av[u][r] += pv_;
        float oth = __shfl_xor(pv_, 1);
        int row = 16 * rt + 4 * g + r;
        if (!(lane & 1)) {
          int col = colb + lx;            // even
          unsigned wd = (unsigned)f2bf(pv_) | ((unsigned)f2bf(oth) << 16);
          *(unsigned*)(Phi + row * 1152 + ((((col >> 3)) ^ (row & 7)) << 4) + (col & 7) * 2) = wd;
        } else {
          int col = colb + lx - 1;        // even base of pair
          unsigned short e0 = f2bf(oth - bf2f(f2bf(oth)));
          unsigned short e1 = f2bf(pv_ - bf2f(f2bf(pv_)));
          unsigned wd = (unsigned)e0 | ((unsigned)e1 << 16);
          *(unsigned*)(Plo + row * 1152 + ((((col >> 3)) ^ (row & 7)) << 4) + (col & 7) * 2) = wd;
        }
      }
    }

    // ---- PV: O[16x16 per wave] over 18 V-chunks ----
    f32x4 O = {0.f, 0.f, 0.f, 0.f};
    const int prow = 16 * rt + lx;
    const int vd = 16 * par + lx;
    #pragma unroll
    for (int vc = 0; vc < 18; ++vc) {
      __syncthreads();                    // vc=0: P + V0 visible
      if (vc < 17) vwrite(KV + ((vc + 1) & 1) * 4096, ld);
      if (vc < 16) ld = gload(512, vc + 2);
      int slot = 4 * vc + g;
      int poff = prow * 1152 + ((slot ^ (prow & 7)) << 4);
      s16x8 ahi = *(const s16x8*)(Phi + poff);
      s16x8 alo = *(const s16x8*)(Plo + poff);
      unsigned char* vb = KV + (vc & 1) * 4096;
      s16x8 bhi = *(const s16x8*)(vb + vd * 128 + (((g) ^ (vd & 7)) << 4));
      s16x8 blo = *(const s16x8*)(vb + vd * 128 + (((g + 4) ^ (vd & 7)) << 4));
      O = __builtin_amdgcn_mfma_f32_16x16x32_bf16(alo, bhi, O, 0, 0, 0);
      O = __builtin_amdgcn_mfma_f32_16x16x32_bf16(ahi, blo, O, 0, 0, 0);
      O = __builtin_amdgcn_mfma_f32_16x16x32_bf16(ahi, bhi, O, 0, 0, 0);
    }
    __syncthreads();                      // D: all PV reads done
    // stage O [32][32] f32 in kvbuf0, then coalesced write
    #pragma unroll
    for (int r = 0; r < 4; ++r) {
      int row = 16 * rt + 4 * g + r;
      int col = 16 * par + lx;
      *(float*)(KV + (row * 32 + col) * 4) = O[r];
    }
    __syncthreads();                      // E
    {
      float4 ov = *(const float4*)(KV + ((tid >> 3) * 32 + (tid & 7) * 4) * 4);
      *(float4*)(obuf + (base_s + q0 + (tid >> 3)) * DIM + h * 32 + (tid & 7) * 4) = ov;
    }
  }

  // ---- head-averaged attention: frag regs -> LDS fp32 [32][576] -> coalesced global ----
  __syncthreads();
  float* avl = (float*)sm;
  #pragma unroll
  for (int u = 0; u < 18; ++u) {
    int colb = (2 * u + par) * 16 + lx;
    #pragma unroll
    for (int r = 0; r < 4; ++r) {
      int row = 16 * rt + 4 * g + r;
      avl[row * 576 + colb] = av[u][r];
    }
  }
  __syncthreads();
  {
    int row = tid >> 3;
    int c0 = (tid & 7) * 4;
    size_t gb = (size_t)pair * SS + (size_t)(q0 + row) * SEQ;
    #pragma unroll
    for (int u2 = 0; u2 < 18; ++u2) {
      int col = c0 + 32 * u2;
      float4 a = *(const float4*)(avl + row * 576 + col);
      a.x *= 0.125f; a.y *= 0.125f; a.z *= 0.125f; a.w *= 0.125f;
      *(float4*)(attn_l + gb + col) = a;
    }
  }
}

// ---------------- head ----------------
__global__ void k_feat(const float* __restrict__ pe, float* __restrict__ feat) {
  int idx = blockIdx.x * 256 + threadIdx.x;
  int b = idx >> 10, c = idx & 1023;
  int ni = c >> 8, d = c & 255;
  const float* p = pe + (size_t)(ni * BATCH + b) * SEQ * DIM + d;
  float sum = 0.f;
  for (int s = 0; s < SEQ; ++s) sum += p[(size_t)s * DIM];
  feat[idx] = sum * (1.0f / 576.0f);
}

__global__ void k_head1(const float* __restrict__ feat, const float* __restrict__ w1,
                        const float* __restrict__ b1, float* __restrict__ h) {
  int idx = blockIdx.x * 256 + threadIdx.x;
  int b = idx >> 9, m = idx & 511;
  const float* f = feat + b * 1024;
  const float* w = w1 + (size_t)m * 1024;
  float acc = 0.f;
  for (int k = 0; k < 1024; ++k) acc = fmaf(f[k], w[k], acc);
  h[idx] = fmaxf(acc + b1[m], 0.f);
}

__global__ void k_head2(const float* __restrict__ h, const float* __restrict__ w2,
                        const float* __restrict__ b2, float* __restrict__ out) {
  int b = blockIdx.x;
  int lane = threadIdx.x;
  float acc = 0.f;
  for (int m = lane; m < 512; m += 64) acc = fmaf(h[b * 512 + m], w2[m], acc);
  #pragma unroll
  for (int m = 1; m < 64; m <<= 1) acc += __shfl_xor(acc, m, 64);
  if (lane == 0) out[b] = acc + b2[0];
}

extern "C" void kernel_launch(void* const* d_in, const int* in_sizes, int n_in,
                              void* d_out, int out_size, void* d_ws, size_t ws_size,
                              hipStream_t stream) {
  const float* x      = (const float*)d_in[0];
  const float* conv_w = (const float*)d_in[1];
  const float* conv_b = (const float*)d_in[2];
  const float* pos    = (const float*)d_in[3];
  const float* in_w   = (const float*)d_in[4];
  const float* in_b   = (const float*)d_in[5];
  const float* ow     = (const float*)d_in[6];
  const float* ob     = (const float*)d_in[7];
  const float* w1     = (const float*)d_in[8];
  const float* b1     = (const float*)d_in[9];
  const float* w2     = (const float*)d_in[10];
  const float* b2     = (const float*)d_in[11];
  float* out  = (float*)d_out;
  float* attn = out + 8;

  float* ws   = (float*)d_ws;
  float* wT   = ws;                         // 786432
  float* peA  = wT + 786432;                // 4718592
  float* qkv  = peA + 4718592;              // 14155776
  float* oB   = qkv + 14155776;             // 4718592
  float* feat = oB + 4718592;               // 8192
  float* hbuf = feat + 8192;                // 4096

  k_transpose_w<<<3072, 256, 0, stream>>>(conv_w, wT);
  k_patch_embed<<<dim3(72, BATCH, NIMG), 256, 0, stream>>>(x, wT, conv_b, pos, peA);
  for (int l = 0; l < NLAYER; ++l) {
    k_gemm_bt<<<dim3(6, 144), 256, 0, stream>>>(
        peA, in_w + (size_t)l * TD * DIM, in_b + l * TD, qkv, 18432, TD, DIM);
    k_attn2<<<576, 256, 0, stream>>>(
        qkv, oB, attn + (size_t)l * NIMG * BATCH * SS);
    k_gemm_bt<<<dim3(2, 144), 256, 0, stream>>>(
        oB, ow + (size_t)l * DIM * DIM, ob + l * DIM, peA, 18432, DIM, DIM);
  }
  k_feat<<<32, 256, 0, stream>>>(peA, feat);
  k_head1<<<16, 256, 0, stream>>>(feat, w1, b1, hbuf);
  k_head2<<<BATCH, 64, 0, stream>>>(hbuf, w2, b2, out);
}

// Round 4
// 3239.762 us; speedup vs baseline: 2.4198x; 2.0021x over previous
//
#include <hip/hip_runtime.h>

#define NIMG 4
#define BATCH 8
#define SEQ 576
#define DIM 256
#define NHEAD 8
#define DHEAD 32
#define NLAYER 6
#define TD 768
#define KPATCH 768
#define MLPD 512
#define SS (SEQ*SEQ)

typedef float f32x4 __attribute__((ext_vector_type(4)));
typedef short s16x8 __attribute__((ext_vector_type(8)));
typedef unsigned short ush;

static __device__ __forceinline__ ush f2bf(float f) {
  __bf16 h = (__bf16)f;
  return __builtin_bit_cast(ush, h);
}
static __device__ __forceinline__ float bf2f(ush u) {
  return __builtin_bit_cast(float, (unsigned)u << 16);
}

// ---------------- conv weight transpose ----------------
__global__ void k_transpose_w(const float* __restrict__ w, float* __restrict__ wT) {
  int idx = blockIdx.x * 256 + threadIdx.x;
  int d = idx & 255;
  int t = idx >> 8;
  int ni = t / 768;
  int k = t - ni * 768;
  wT[idx] = w[(size_t)ni * 196608 + (size_t)d * 768 + k];
}

// ---------------- patch embed ----------------
__global__ __launch_bounds__(256) void k_patch_embed(
    const float* __restrict__ x, const float* __restrict__ wT,
    const float* __restrict__ cb, const float* __restrict__ pos,
    float* __restrict__ pe) {
  __shared__ float patch[8][KPATCH];
  const int ni = blockIdx.z, b = blockIdx.y;
  const int s0 = blockIdx.x * 8;
  const int tid = threadIdx.x;
  for (int e = tid; e < 8 * KPATCH; e += 256) {
    int sp = e / KPATCH, k = e - sp * KPATCH;
    int s = s0 + sp;
    int c = k >> 8, r = k & 255, i = r >> 4, j = r & 15;
    int py = s / 24, px = s - py * 24;
    patch[sp][k] = x[((size_t)(b * 12 + ni * 3 + c) * 384 + py * 16 + i) * 384 + px * 16 + j];
  }
  __syncthreads();
  const int d = tid;
  float acc[8] = {};
  const float* wp = wT + (size_t)ni * 196608 + d;
  for (int k = 0; k < KPATCH; ++k) {
    float wv = wp[(size_t)k * 256];
    #pragma unroll
    for (int sp = 0; sp < 8; ++sp) acc[sp] = fmaf(patch[sp][k], wv, acc[sp]);
  }
  float bias = cb[ni * 256 + d];
  size_t base = ((size_t)(ni * BATCH + b) * SEQ + s0) * DIM + d;
  #pragma unroll
  for (int sp = 0; sp < 8; ++sp)
    pe[base + (size_t)sp * 256] = acc[sp] + bias + pos[(s0 + sp) * 256 + d];
}

// ---------------- fp32 GEMM: C = A @ W^T + bias ----------------
// MODE 0: plain fp32 out to C[M,N].
// MODE 1 (qkv): N=768. cols 0..511 -> bf16 hi/lo planes qh/ql [M][512]
//   (cols<256 scaled by 1/sqrt(32)); cols 512..767 -> fp32 vout [M][256].
template <int MODE>
__global__ __launch_bounds__(256) void k_gemm_bt(
    const float* __restrict__ A, const float* __restrict__ W,
    const float* __restrict__ bias, float* __restrict__ C,
    ush* __restrict__ qh, ush* __restrict__ ql, float* __restrict__ vout,
    int M, int N, int K) {
  __shared__ float As[16][132];
  __shared__ float Ws[16][132];
  const int bm = blockIdx.y * 128, bn = blockIdx.x * 128;
  const int tid = threadIdx.x;
  const int tx = tid & 15, ty = tid >> 4;
  float acc[8][8] = {};
  for (int k0 = 0; k0 < K; k0 += 16) {
    __syncthreads();
    #pragma unroll
    for (int half = 0; half < 2; ++half) {
      int f = tid + half * 256;
      int r = f >> 2, ko = f & 3;
      float4 va = reinterpret_cast<const float4*>(A + (size_t)(bm + r) * K + k0)[ko];
      As[ko * 4 + 0][r] = va.x; As[ko * 4 + 1][r] = va.y;
      As[ko * 4 + 2][r] = va.z; As[ko * 4 + 3][r] = va.w;
      float4 vw = reinterpret_cast<const float4*>(W + (size_t)(bn + r) * K + k0)[ko];
      Ws[ko * 4 + 0][r] = vw.x; Ws[ko * 4 + 1][r] = vw.y;
      Ws[ko * 4 + 2][r] = vw.z; Ws[ko * 4 + 3][r] = vw.w;
    }
    __syncthreads();
    #pragma unroll
    for (int kk = 0; kk < 16; ++kk) {
      float a[8], bv[8];
      #pragma unroll
      for (int i = 0; i < 8; ++i) a[i] = As[kk][ty + 16 * i];
      #pragma unroll
      for (int j = 0; j < 8; ++j) bv[j] = Ws[kk][tx + 16 * j];
      #pragma unroll
      for (int i = 0; i < 8; ++i)
        #pragma unroll
        for (int j = 0; j < 8; ++j)
          acc[i][j] = fmaf(a[i], bv[j], acc[i][j]);
    }
  }
  if (MODE == 0) {
    #pragma unroll
    for (int i = 0; i < 8; ++i) {
      size_t row = (size_t)(bm + ty + 16 * i) * N + bn;
      #pragma unroll
      for (int j = 0; j < 8; ++j)
        C[row + tx + 16 * j] = acc[i][j] + bias[bn + tx + 16 * j];
    }
  } else {
    if (bn < 512) {
      const float sc = (bn < 256) ? 0.17677669529663687f : 1.0f;
      #pragma unroll
      for (int i = 0; i < 8; ++i) {
        size_t row = (size_t)(bm + ty + 16 * i) * 512 + bn;
        #pragma unroll
        for (int j = 0; j < 8; ++j) {
          float v = (acc[i][j] + bias[bn + tx + 16 * j]) * sc;
          ush hb = f2bf(v);
          qh[row + tx + 16 * j] = hb;
          ql[row + tx + 16 * j] = f2bf(v - bf2f(hb));
        }
      }
    } else {
      #pragma unroll
      for (int i = 0; i < 8; ++i) {
        size_t row = (size_t)(bm + ty + 16 * i) * 256 + (bn - 512);
        #pragma unroll
        for (int j = 0; j < 8; ++j)
          vout[row + tx + 16 * j] = acc[i][j] + bias[bn + tx + 16 * j];
      }
    }
  }
}

// ---------------- V transpose+split: v fp32 [18432][256] -> vT hi/lo [8192][576] ----------------
__global__ __launch_bounds__(256) void k_vt(
    const float* __restrict__ v, ush* __restrict__ vTh, ush* __restrict__ vTl) {
  __shared__ float lds[32 * 260];
  const int blk = blockIdx.x;           // 576
  const int pair = blk / 18, stile = blk % 18;
  const int s0 = stile * 32;
  const int tid = threadIdx.x;
  const size_t rbase = ((size_t)pair * 576 + s0) * 256;
  #pragma unroll
  for (int i = 0; i < 8; ++i) {
    int flat = tid + i * 256;           // 2048 float4s
    int s = flat >> 6, c4 = (flat & 63) * 4;
    float4 vv = *(const float4*)(v + rbase + (size_t)s * 256 + c4);
    lds[s * 260 + c4 + 0] = vv.x; lds[s * 260 + c4 + 1] = vv.y;
    lds[s * 260 + c4 + 2] = vv.z; lds[s * 260 + c4 + 3] = vv.w;
  }
  __syncthreads();
  const int h = tid >> 5, d = tid & 31;
  size_t obase = ((size_t)(pair * 8 + h) * 32 + d) * 576 + s0;
  unsigned* oh = (unsigned*)(vTh + obase);
  unsigned* ol = (unsigned*)(vTl + obase);
  #pragma unroll
  for (int sp = 0; sp < 16; ++sp) {
    float a = lds[(2 * sp) * 260 + tid];
    float b = lds[(2 * sp + 1) * 260 + tid];
    ush ha = f2bf(a), hb = f2bf(b);
    ush la = f2bf(a - bf2f(ha)), lb = f2bf(b - bf2f(hb));
    oh[sp] = (unsigned)ha | ((unsigned)hb << 16);
    ol[sp] = (unsigned)la | ((unsigned)lb << 16);
  }
}

// ---------------- MFMA fused attention, swapped-operand form ----------------
// block: (pair, 32 q-rows); 4 waves = 2 q-tiles x 2 (key-half / d-tile); heads looped.
// S^T = K @ Q^T (full 576 keys in regs), softmax once, P->LDS, O^T = V^T @ P^T.
// attn-avg: per-head exclusive global RMW from Pbuf.
__global__ __launch_bounds__(256, 3) void k_attn3(
    const ush* __restrict__ qkh, const ush* __restrict__ qkl,
    const ush* __restrict__ vTh, const ush* __restrict__ vTl,
    float* __restrict__ obuf, float* __restrict__ attn_l) {
  __shared__ __align__(16) unsigned char sm[49664];
  unsigned char* KV = sm;               // 24576: K [192 rows][128B] or V [64 rows][384B]
  unsigned char* Pb = sm + 24576;       // 24576: P [2 planes][32 q][384B]
  float* scrM = (float*)(sm + 49152);   // 64 floats
  float* scrZ = scrM + 64;              // 64 floats

  const int tid = threadIdx.x;
  const int bid = blockIdx.x;
  const int pair = bid & 31;            // same XCD for same pair (32 % 8 == 0)
  const int q0 = (bid >> 5) * 32;
  const int lane = tid & 63;
  const int w = tid >> 6;
  const int qt = w & 1, kh = w >> 1;
  const int g = lane >> 4, lx = lane & 15;
  const size_t base_s = (size_t)pair * SEQ;

  s16x8 kld[6], vld[6];

  auto k_issue = [&](int t, int hh) {
    #pragma unroll
    for (int it = 0; it < 6; ++it) {
      int flat = tid + it * 256, row = flat >> 3, blk = flat & 7;
      const ush* src = (blk < 4) ? qkh : qkl;
      kld[it] = *(const s16x8*)(src + (base_s + t * 192 + row) * 512 + 256 + hh * 32 + (blk & 3) * 8);
    }
  };
  auto k_write = [&]() {
    #pragma unroll
    for (int it = 0; it < 6; ++it) {
      int flat = tid + it * 256, row = flat >> 3, blk = flat & 7;
      *(s16x8*)(KV + row * 128 + ((blk ^ (row & 7)) << 4)) = kld[it];
    }
  };
  auto v_issue = [&](int t, int hh) {
    int row = tid >> 2;
    int plane = row >> 5, d = row & 31;
    const ush* src = plane ? vTl : vTh;
    const ush* p = src + ((size_t)((pair * 8 + hh) * 32 + d)) * 576 + t * 192;
    #pragma unroll
    for (int it = 0; it < 6; ++it) {
      int blk = (tid & 3) * 6 + it;
      vld[it] = *(const s16x8*)(p + blk * 8);
    }
  };
  auto v_write = [&]() {
    int row = tid >> 2;
    int d = row & 31;
    #pragma unroll
    for (int it = 0; it < 6; ++it) {
      int blk = (tid & 3) * 6 + it;
      *(s16x8*)(KV + row * 384 + ((blk ^ (d & 7)) << 4)) = vld[it];
    }
  };

  k_issue(0, 0);

  for (int h = 0; h < NHEAD; ++h) {
    // Q^T B-frags (hi/lo), direct from global (pre-scaled in GEMM epilogue)
    const ush* qp = qkh + (base_s + q0 + qt * 16 + lx) * 512 + h * 32 + g * 8;
    const ush* qp2 = qkl + (base_s + q0 + qt * 16 + lx) * 512 + h * 32 + g * 8;
    s16x8 qhi = *(const s16x8*)qp;
    s16x8 qlo = *(const s16x8*)qp2;

    f32x4 S[18];
    #pragma unroll
    for (int u = 0; u < 18; ++u) S[u] = f32x4{0.f, 0.f, 0.f, 0.f};

    // ---- QK: 3 thirds ----
    #pragma unroll
    for (int t = 0; t < 3; ++t) {
      __syncthreads();                  // KV free
      k_write();
      if (t < 2) k_issue(t + 1, h); else v_issue(0, h);
      __syncthreads();                  // K(t) visible
      #pragma unroll
      for (int i = 0; i < 6; ++i) {
        int row = (kh * 6 + i) * 16 + lx;
        s16x8 khi = *(const s16x8*)(KV + row * 128 + ((g ^ (row & 7)) << 4));
        s16x8 klo = *(const s16x8*)(KV + row * 128 + (((4 + g) ^ (row & 7)) << 4));
        f32x4 a = S[t * 6 + i];
        a = __builtin_amdgcn_mfma_f32_16x16x32_bf16(khi, qhi, a, 0, 0, 0);
        a = __builtin_amdgcn_mfma_f32_16x16x32_bf16(khi, qlo, a, 0, 0, 0);
        a = __builtin_amdgcn_mfma_f32_16x16x32_bf16(klo, qhi, a, 0, 0, 0);
        S[t * 6 + i] = a;
      }
    }

    // ---- softmax over full 576 keys (wave holds 288; partner has rest) ----
    float m = -1e30f;
    #pragma unroll
    for (int u = 0; u < 18; ++u)
      #pragma unroll
      for (int r = 0; r < 4; ++r) m = fmaxf(m, S[u][r]);
    m = fmaxf(m, __shfl_xor(m, 16));
    m = fmaxf(m, __shfl_xor(m, 32));
    if (lane < 16) scrM[kh * 32 + qt * 16 + lx] = m;
    __syncthreads();                    // S1 (also: QK reads of KV done)
    m = fmaxf(m, scrM[(kh ^ 1) * 32 + qt * 16 + lx]);
    float Z = 0.f;
    #pragma unroll
    for (int u = 0; u < 18; ++u)
      #pragma unroll
      for (int r = 0; r < 4; ++r) {
        float e = __expf(S[u][r] - m);
        S[u][r] = e;
        Z += e;
      }
    Z += __shfl_xor(Z, 16);
    Z += __shfl_xor(Z, 32);
    if (lane < 16) scrZ[kh * 32 + qt * 16 + lx] = Z;
    __syncthreads();                    // S2
    float inv = 1.0f / (Z + scrZ[(kh ^ 1) * 32 + qt * 16 + lx]);

    // ---- PV: 3 thirds ----
    f32x4 O = {0.f, 0.f, 0.f, 0.f};
    #pragma unroll
    for (int t = 0; t < 3; ++t) {
      if (t > 0) __syncthreads();       // PV(t-1) reads done
      v_write();
      if (t < 2) v_issue(t + 1, h); else if (h < 7) k_issue(0, h + 1);
      // P-write(t): wave owns keys [t*192 + kh*96, +96)
      {
        int q = qt * 16 + lx;
        int swz = (q & 7);
        #pragma unroll
        for (int i = 0; i < 6; ++i) {
          int ktl = kh * 6 + i;
          #pragma unroll
          for (int p = 0; p < 2; ++p) {
            float v0 = S[t * 6 + i][2 * p] * inv;
            float v1 = S[t * 6 + i][2 * p + 1] * inv;
            ush h0 = f2bf(v0), h1 = f2bf(v1);
            ush l0 = f2bf(v0 - bf2f(h0)), l1 = f2bf(v1 - bf2f(h1));
            int koff = 4 * g + 2 * p;
            int blk = ktl * 2 + (koff >> 3);
            int base = q * 384 + ((blk ^ swz) << 4) + (koff & 7) * 2;
            *(unsigned*)(Pb + base) = (unsigned)h0 | ((unsigned)h1 << 16);
            *(unsigned*)(Pb + 12288 + base) = (unsigned)l0 | ((unsigned)l1 << 16);
          }
        }
      }
      __syncthreads();                  // V(t) + P(t) visible
      // PV mfma: wave (qt, dt=kh)
      {
        int dd = kh * 16 + lx;
        int q = qt * 16 + lx;
        #pragma unroll
        for (int kc = 0; kc < 6; ++kc) {
          int vs = ((kc * 4 + g) ^ (dd & 7)) << 4;
          int ps = ((kc * 4 + g) ^ (q & 7)) << 4;
          s16x8 vhi = *(const s16x8*)(KV + dd * 384 + vs);
          s16x8 vlo = *(const s16x8*)(KV + (32 + dd) * 384 + vs);
          s16x8 phi = *(const s16x8*)(Pb + q * 384 + ps);
          s16x8 plo = *(const s16x8*)(Pb + 12288 + q * 384 + ps);
          O = __builtin_amdgcn_mfma_f32_16x16x32_bf16(vhi, phi, O, 0, 0, 0);
          O = __builtin_amdgcn_mfma_f32_16x16x32_bf16(vhi, plo, O, 0, 0, 0);
          O = __builtin_amdgcn_mfma_f32_16x16x32_bf16(vlo, phi, O, 0, 0, 0);
        }
      }
      // attn-avg RMW from Pbuf (block-exclusive rows; no atomics)
      {
        int q = tid >> 3;
        float* gp = attn_l + (size_t)pair * SS + (size_t)(q0 + q) * SEQ + t * 192;
        #pragma unroll
        for (int i = 0; i < 3; ++i) {
          int blk = (tid & 7) + 8 * i;
          int off = q * 384 + ((blk ^ (q & 7)) << 4);
          s16x8 ph = *(const s16x8*)(Pb + off);
          s16x8 pl = *(const s16x8*)(Pb + 12288 + off);
          float vals[8];
          #pragma unroll
          for (int j = 0; j < 8; ++j)
            vals[j] = (bf2f((ush)ph[j]) + bf2f((ush)pl[j])) * 0.125f;
          float* dst = gp + blk * 8;
          if (h == 0) {
            *(float4*)dst = float4{vals[0], vals[1], vals[2], vals[3]};
            *(float4*)(dst + 4) = float4{vals[4], vals[5], vals[6], vals[7]};
          } else {
            float4 a = *(const float4*)dst;
            float4 b = *(const float4*)(dst + 4);
            a.x += vals[0]; a.y += vals[1]; a.z += vals[2]; a.w += vals[3];
            b.x += vals[4]; b.y += vals[5]; b.z += vals[6]; b.w += vals[7];
            *(float4*)dst = a;
            *(float4*)(dst + 4) = b;
          }
        }
      }
    }

    // ---- O^T -> obuf via LDS transpose ----
    __syncthreads();                    // PV(2) done; KV free
    float* Ol = (float*)KV;             // [32 q][33]
    #pragma unroll
    for (int r = 0; r < 4; ++r)
      Ol[(qt * 16 + lx) * 33 + kh * 16 + 4 * g + r] = O[r];
    __syncthreads();
    {
      int q = tid >> 3, d4 = (tid & 7) * 4;
      float4 o = {Ol[q * 33 + d4], Ol[q * 33 + d4 + 1], Ol[q * 33 + d4 + 2], Ol[q * 33 + d4 + 3]};
      *(float4*)(obuf + (base_s + q0 + q) * 256 + h * 32 + d4) = o;
    }
  }
}

// ---------------- head ----------------
__global__ void k_feat(const float* __restrict__ pe, float* __restrict__ feat) {
  int idx = blockIdx.x * 256 + threadIdx.x;
  int b = idx >> 10, c = idx & 1023;
  int ni = c >> 8, d = c & 255;
  const float* p = pe + (size_t)(ni * BATCH + b) * SEQ * DIM + d;
  float sum = 0.f;
  for (int s = 0; s < SEQ; ++s) sum += p[(size_t)s * DIM];
  feat[idx] = sum * (1.0f / 576.0f);
}

__global__ void k_head1(const float* __restrict__ feat, const float* __restrict__ w1,
                        const float* __restrict__ b1, float* __restrict__ h) {
  int idx = blockIdx.x * 256 + threadIdx.x;
  int b = idx >> 9, m = idx & 511;
  const float* f = feat + b * 1024;
  const float* w = w1 + (size_t)m * 1024;
  float acc = 0.f;
  for (int k = 0; k < 1024; ++k) acc = fmaf(f[k], w[k], acc);
  h[idx] = fmaxf(acc + b1[m], 0.f);
}

__global__ void k_head2(const float* __restrict__ h, const float* __restrict__ w2,
                        const float* __restrict__ b2, float* __restrict__ out) {
  int b = blockIdx.x;
  int lane = threadIdx.x;
  float acc = 0.f;
  for (int m = lane; m < 512; m += 64) acc = fmaf(h[b * 512 + m], w2[m], acc);
  #pragma unroll
  for (int m = 1; m < 64; m <<= 1) acc += __shfl_xor(acc, m, 64);
  if (lane == 0) out[b] = acc + b2[0];
}

extern "C" void kernel_launch(void* const* d_in, const int* in_sizes, int n_in,
                              void* d_out, int out_size, void* d_ws, size_t ws_size,
                              hipStream_t stream) {
  const float* x      = (const float*)d_in[0];
  const float* conv_w = (const float*)d_in[1];
  const float* conv_b = (const float*)d_in[2];
  const float* pos    = (const float*)d_in[3];
  const float* in_w   = (const float*)d_in[4];
  const float* in_b   = (const float*)d_in[5];
  const float* ow     = (const float*)d_in[6];
  const float* ob     = (const float*)d_in[7];
  const float* w1     = (const float*)d_in[8];
  const float* b1     = (const float*)d_in[9];
  const float* w2     = (const float*)d_in[10];
  const float* b2     = (const float*)d_in[11];
  float* out  = (float*)d_out;
  float* attn = out + 8;

  // workspace layout (floats):
  float* ws   = (float*)d_ws;
  float* wT   = ws;                        // 786432
  float* peA  = wT + 786432;               // 4718592
  float* oB   = peA + 4718592;             // 4718592  (aliases qkv-V fp32 scratch)
  float* feat = oB + 4718592;              // 8192
  float* hbuf = feat + 8192;               // 4096
  ush* qkh = (ush*)(hbuf + 4096);          // 9437184 ush
  ush* qkl = qkh + 9437184;                // 9437184 ush
  ush* vTh = qkl + 9437184;                // 4718592 ush
  ush* vTl = vTh + 4718592;                // 4718592 ush

  k_transpose_w<<<3072, 256, 0, stream>>>(conv_w, wT);
  k_patch_embed<<<dim3(72, BATCH, NIMG), 256, 0, stream>>>(x, wT, conv_b, pos, peA);
  for (int l = 0; l < NLAYER; ++l) {
    k_gemm_bt<1><<<dim3(6, 144), 256, 0, stream>>>(
        peA, in_w + (size_t)l * TD * DIM, in_b + l * TD, nullptr,
        qkh, qkl, oB, 18432, TD, DIM);
    k_vt<<<576, 256, 0, stream>>>(oB, vTh, vTl);
    k_attn3<<<576, 256, 0, stream>>>(
        qkh, qkl, vTh, vTl, oB, attn + (size_t)l * NIMG * BATCH * SS);
    k_gemm_bt<0><<<dim3(2, 144), 256, 0, stream>>>(
        oB, ow + (size_t)l * DIM * DIM, ob + l * DIM, peA,
        nullptr, nullptr, nullptr, 18432, DIM, DIM);
  }
  k_feat<<<32, 256, 0, stream>>>(peA, feat);
  k_head1<<<16, 256, 0, stream>>>(feat, w1, b1, hbuf);
  k_head2<<<BATCH, 64, 0, stream>>>(hbuf, w2, b2, out);
}